// Round 5
// baseline (255.396 us; speedup 1.0000x reference)
//
#include <hip/hip_runtime.h>
#include <hip/hip_bf16.h>
#include <stdint.h>

typedef __bf16 bf16x8 __attribute__((ext_vector_type(8)));
typedef float floatx4 __attribute__((ext_vector_type(4)));

// ---------------------------------------------------------------------------
// Async global->LDS 16B copy (wave-uniform LDS base + lane*16; per-lane
// global address OK).
// ---------------------------------------------------------------------------
__device__ __forceinline__ void async_copy16(void* lds, const void* g) {
    __builtin_amdgcn_global_load_lds(
        (const __attribute__((address_space(1))) unsigned int*)g,
        (__attribute__((address_space(3))) unsigned int*)lds,
        16, 0, 0);
}

// ---------------------------------------------------------------------------
// Kron prep: Wrot[o,d] = sum_k kron(K1,K2,K3)[d,k] * W[o,k], bf16 out.
// d = (d1*8 + d2)*40 + d3 ; k = (k1*8 + k2)*40 + k3.  One block per row o.
// ---------------------------------------------------------------------------
__global__ __launch_bounds__(256)
void kron_rotate_w(const float* __restrict__ W,
                   const float* __restrict__ K1,
                   const float* __restrict__ K2,
                   const float* __restrict__ K3,
                   __hip_bfloat16* __restrict__ Wrot) {
    __shared__ __align__(16) float w0[1280];   // W row, then stage-2 result
    __shared__ __align__(16) float t1[1280];
    __shared__ __align__(16) float k3s[1600];
    __shared__ float k2s[64];
    __shared__ float k1s[16];
    const int o   = blockIdx.x;
    const int tid = threadIdx.x;

    for (int i = tid; i < 1280; i += 256) w0[i] = W[o * 1280 + i];
    for (int i = tid; i < 1600; i += 256) k3s[i] = K3[i];
    if (tid < 64) k2s[tid] = K2[tid];
    if (tid < 16) k1s[tid] = K1[tid];
    __syncthreads();

    // stage 1: t1[p*40 + d3] = sum_k3 w0[p*40+k3] * K3[d3,k3]  (float4 LDS)
    for (int i = tid; i < 1280; i += 256) {
        const int p = i / 40, d3 = i % 40;
        const float4* w4 = (const float4*)(w0 + p * 40);
        const float4* k4 = (const float4*)(k3s + d3 * 40);
        float acc = 0.f;
#pragma unroll
        for (int t = 0; t < 10; ++t) {
            const float4 a = w4[t], b = k4[t];
            acc += a.x * b.x + a.y * b.y + a.z * b.z + a.w * b.w;
        }
        t1[i] = acc;
    }
    __syncthreads();

    // stage 2: w0[(k1*8+d2)*40+d3] = sum_k2 t1[(k1*8+k2)*40+d3] * K2[d2,k2]
    for (int i = tid; i < 1280; i += 256) {
        const int d3 = i % 40, pd = i / 40;
        const int k1 = pd >> 3, d2 = pd & 7;
        float acc = 0.f;
#pragma unroll
        for (int k2 = 0; k2 < 8; ++k2) acc += t1[(k1 * 8 + k2) * 40 + d3] * k2s[d2 * 8 + k2];
        w0[i] = acc;
    }
    __syncthreads();

    // stage 3: Wrot[o,(d1*8+d2)*40+d3] = sum_k1 w0[(k1*8+d2)*40+d3] * K1[d1,k1]
    for (int i = tid; i < 1280; i += 256) {
        const int d3 = i % 40, pd = i / 40;
        const int d1 = pd >> 3, d2 = pd & 7;
        float acc = 0.f;
#pragma unroll
        for (int k1 = 0; k1 < 4; ++k1) acc += w0[(k1 * 8 + d2) * 40 + d3] * k1s[d1 * 4 + k1];
        Wrot[(size_t)o * 1280 + i] = __float2bfloat16(acc);
    }
}

// ---------------------------------------------------------------------------
// Main GEMM: C[m,n] = sum_k A[m,k] * B[n,k]
//   A: fp32 [M,K] (x, read directly — no convert pass), staged via registers
//      with in-flight fp32->bf16 cvt and cross-iteration PREFETCH.
//   B: bf16 [N,K] (Wrot), staged via global_load_lds width=16.
// 128x128 tile, 256 threads = 4 waves (2x2), 64x64/wave via 4x4
// mfma_f32_16x16x32_bf16, BK=64. XOR-swizzled k-granules (0 conflicts, r4):
// LDS granule (m, p) holds k-granule p ^ (m&7).
// ---------------------------------------------------------------------------
#define BM 128
#define BN 128
#define BK 64

__global__ __launch_bounds__(256)
void gemm_bt(const float* __restrict__ A,            // [M,K] fp32
             const __hip_bfloat16* __restrict__ B,   // [N,K] bf16
             float* __restrict__ C,                  // [M,N] fp32
             int M, int N, int K) {
    __shared__ bf16x8 As[1024];   // 128 rows * 8 granules * 16B = 16 KiB
    __shared__ bf16x8 Bs[1024];

    const int tid  = threadIdx.x;
    const int wave = tid >> 6;
    const int lane = tid & 63;
    const int q    = lane >> 4;
    const int r16  = lane & 15;

    const int nTilesN = N / BN;
    const int bn = blockIdx.x % nTilesN;
    const int bm = blockIdx.x / nTilesN;
    const int tileM = bm * BM, tileN = bn * BN;
    const int wm = wave >> 1, wn = wave & 1;

    floatx4 acc[4][4];
#pragma unroll
    for (int i = 0; i < 4; ++i)
#pragma unroll
        for (int j = 0; j < 4; ++j) acc[i][j] = (floatx4){0.f, 0.f, 0.f, 0.f};

    // Staging granule for chunk t: g = wave*256 + t*64 + lane,
    // row m = g>>3, phys slot p = g&7, data k-granule kv = p ^ (m&7).
    // Per-thread A prefetch: 4 granules * 8 fp32 = 8 float4 regs.
    int amrow[4], akv[4];
#pragma unroll
    for (int t = 0; t < 4; ++t) {
        const int g = wave * 256 + t * 64 + lane;
        amrow[t] = g >> 3;
        akv[t]   = (g & 7) ^ (amrow[t] & 7);
    }

    float4 apre[4][2];
    // prologue: issue A loads for kt = 0
#pragma unroll
    for (int t = 0; t < 4; ++t) {
        const float* ga = A + (size_t)(tileM + amrow[t]) * K + akv[t] * 8;
        apre[t][0] = *(const float4*)ga;
        apre[t][1] = *(const float4*)(ga + 4);
    }

    for (int kt = 0; kt < K; kt += BK) {
        __syncthreads();   // previous iteration's LDS readers done

        // cvt + ds_write A (consumes prefetched regs), contiguous b128 writes
#pragma unroll
        for (int t = 0; t < 4; ++t) {
            bf16x8 v;
            v[0] = (__bf16)apre[t][0].x; v[1] = (__bf16)apre[t][0].y;
            v[2] = (__bf16)apre[t][0].z; v[3] = (__bf16)apre[t][0].w;
            v[4] = (__bf16)apre[t][1].x; v[5] = (__bf16)apre[t][1].y;
            v[6] = (__bf16)apre[t][1].z; v[7] = (__bf16)apre[t][1].w;
            As[wave * 256 + t * 64 + lane] = v;
        }
        // async-DMA B granules (wave-uniform LDS base + lane*16)
#pragma unroll
        for (int t = 0; t < 4; ++t) {
            const int g  = wave * 256 + t * 64 + lane;
            const int m  = g >> 3;
            const int kv = (g & 7) ^ (m & 7);
            async_copy16(&Bs[wave * 256 + t * 64],
                         B + (size_t)(tileN + m) * K + kt + kv * 8);
        }
        __syncthreads();   // drains B-DMA (vmcnt) + A writes (lgkm)

        // prefetch next iteration's A — latency overlaps the MFMAs below
        if (kt + BK < K) {
#pragma unroll
            for (int t = 0; t < 4; ++t) {
                const float* ga = A + (size_t)(tileM + amrow[t]) * K + (kt + BK) + akv[t] * 8;
                apre[t][0] = *(const float4*)ga;
                apre[t][1] = *(const float4*)(ga + 4);
            }
        }

        // compute: 2 k-steps of 32
#pragma unroll
        for (int s = 0; s < 2; ++s) {
            bf16x8 af[4], bfr[4];
            const int kv = s * 4 + q;
#pragma unroll
            for (int i = 0; i < 4; ++i) {
                const int m = wm * 64 + i * 16 + r16;
                af[i] = As[m * 8 + (kv ^ (m & 7))];
                const int n = wn * 64 + i * 16 + r16;
                bfr[i] = Bs[n * 8 + (kv ^ (n & 7))];
            }
#pragma unroll
            for (int i = 0; i < 4; ++i)
#pragma unroll
                for (int j = 0; j < 4; ++j)
                    acc[i][j] = __builtin_amdgcn_mfma_f32_16x16x32_bf16(
                        af[i], bfr[j], acc[i][j], 0, 0, 0);
        }
    }

    // epilogue: C/D layout col=lane&15, row=quad*4+reg (m89/m91)
#pragma unroll
    for (int i = 0; i < 4; ++i) {
#pragma unroll
        for (int j = 0; j < 4; ++j) {
            const int col = tileN + wn * 64 + j * 16 + r16;
#pragma unroll
            for (int r = 0; r < 4; ++r) {
                const int row = tileM + wm * 64 + i * 16 + q * 4 + r;
                C[(size_t)row * N + col] = acc[i][j][r];
            }
        }
    }
}

// ---------------------------------------------------------------------------
extern "C" void kernel_launch(void* const* d_in, const int* in_sizes, int n_in,
                              void* d_out, int out_size, void* d_ws, size_t ws_size,
                              hipStream_t stream) {
    const float* x  = (const float*)d_in[0];  // [4,4096,1280] fp32
    const float* W  = (const float*)d_in[1];  // [1280,1280]  fp32
    const float* K1 = (const float*)d_in[2];  // [4,4]
    const float* K2 = (const float*)d_in[3];  // [8,8]
    const float* K3 = (const float*)d_in[4];  // [40,40]
    float* out = (float*)d_out;               // [4,4096,1280] fp32

    const int D = 1280;
    const int M = in_sizes[0] / D;            // 16384
    const int N = D, K = D;

    __hip_bfloat16* Wrot = (__hip_bfloat16*)d_ws;   // 3.28 MB

    kron_rotate_w<<<D, 256, 0, stream>>>(W, K1, K2, K3, Wrot);
    gemm_bt<<<(M / BM) * (N / BN), 256, 0, stream>>>(x, Wrot, out, M, N, K);
}

// Round 6
// 240.357 us; speedup vs baseline: 1.0626x; 1.0626x over previous
//
#include <hip/hip_runtime.h>
#include <hip/hip_bf16.h>
#include <stdint.h>

typedef __bf16 bf16x8 __attribute__((ext_vector_type(8)));
typedef float floatx4 __attribute__((ext_vector_type(4)));

// ---------------------------------------------------------------------------
// Async global->LDS 16B copy (wave-uniform LDS base + lane*16; per-lane
// global address OK).
// ---------------------------------------------------------------------------
__device__ __forceinline__ void async_copy16(void* lds, const void* g) {
    __builtin_amdgcn_global_load_lds(
        (const __attribute__((address_space(1))) unsigned int*)g,
        (__attribute__((address_space(3))) unsigned int*)lds,
        16, 0, 0);
}

// ---------------------------------------------------------------------------
// Fused prep, one dispatch:
//   blocks [0, nConv)         : x fp32 -> bf16 (8 elems/thread, float4 loads)
//   blocks [nConv, nConv+1280): Wrot[o,d] = sum_k kron(K1,K2,K3)[d,k] W[o,k]
// d = (d1*8 + d2)*40 + d3 ; k = (k1*8 + k2)*40 + k3.  One kron block per row.
// ---------------------------------------------------------------------------
__global__ __launch_bounds__(256)
void prep(const float* __restrict__ x,
          const float* __restrict__ W,
          const float* __restrict__ K1,
          const float* __restrict__ K2,
          const float* __restrict__ K3,
          __hip_bfloat16* __restrict__ x_bf,
          __hip_bfloat16* __restrict__ Wrot,
          int nConv) {
    const int tid = threadIdx.x;

    if ((int)blockIdx.x < nConv) {
        const size_t i = ((size_t)blockIdx.x * 256 + tid) * 8;
        const float4 a = *(const float4*)(x + i);
        const float4 b = *(const float4*)(x + i + 4);
        bf16x8 v;
        v[0] = (__bf16)a.x; v[1] = (__bf16)a.y; v[2] = (__bf16)a.z; v[3] = (__bf16)a.w;
        v[4] = (__bf16)b.x; v[5] = (__bf16)b.y; v[6] = (__bf16)b.z; v[7] = (__bf16)b.w;
        *(bf16x8*)((__bf16*)x_bf + i) = v;
        return;
    }

    const int o = blockIdx.x - nConv;
    __shared__ __align__(16) float w0[1280];   // W row, then stage-2 result
    __shared__ __align__(16) float t1[1280];
    __shared__ __align__(16) float k3s[1600];
    __shared__ float k2s[64];
    __shared__ float k1s[16];

    for (int i = tid; i < 1280; i += 256) w0[i] = W[o * 1280 + i];
    for (int i = tid; i < 1600; i += 256) k3s[i] = K3[i];
    if (tid < 64) k2s[tid] = K2[tid];
    if (tid < 16) k1s[tid] = K1[tid];
    __syncthreads();

    // stage 1: t1[p*40 + d3] = sum_k3 w0[p*40+k3] * K3[d3,k3]  (float4 LDS)
    for (int i = tid; i < 1280; i += 256) {
        const int p = i / 40, d3 = i % 40;
        const float4* w4 = (const float4*)(w0 + p * 40);
        const float4* k4 = (const float4*)(k3s + d3 * 40);
        float acc = 0.f;
#pragma unroll
        for (int t = 0; t < 10; ++t) {
            const float4 a = w4[t], b = k4[t];
            acc += a.x * b.x + a.y * b.y + a.z * b.z + a.w * b.w;
        }
        t1[i] = acc;
    }
    __syncthreads();

    // stage 2: w0[(k1*8+d2)*40+d3] = sum_k2 t1[(k1*8+k2)*40+d3] * K2[d2,k2]
    for (int i = tid; i < 1280; i += 256) {
        const int d3 = i % 40, pd = i / 40;
        const int k1 = pd >> 3, d2 = pd & 7;
        float acc = 0.f;
#pragma unroll
        for (int k2 = 0; k2 < 8; ++k2) acc += t1[(k1 * 8 + k2) * 40 + d3] * k2s[d2 * 8 + k2];
        w0[i] = acc;
    }
    __syncthreads();

    // stage 3: Wrot[o,(d1*8+d2)*40+d3] = sum_k1 w0[(k1*8+d2)*40+d3] * K1[d1,k1]
    for (int i = tid; i < 1280; i += 256) {
        const int d3 = i % 40, pd = i / 40;
        const int d1 = pd >> 3, d2 = pd & 7;
        float acc = 0.f;
#pragma unroll
        for (int k1 = 0; k1 < 4; ++k1) acc += w0[(k1 * 8 + d2) * 40 + d3] * k1s[d1 * 4 + k1];
        Wrot[(size_t)o * 1280 + i] = __float2bfloat16(acc);
    }
}

// ---------------------------------------------------------------------------
// Main GEMM: C[m,n] = sum_k A[m,k] * B[n,k]   (bf16 in, fp32 out/acc)
// 128x128 tile, 256 threads = 4 waves (2x2), 64x64/wave via 4x4
// mfma_f32_16x16x32_bf16, BK=64. global_load_lds width=16 staging with
// XOR-swizzled k-granules folded into the GLOBAL addresses (0 bank
// conflicts measured, r4): LDS granule (m, p) holds k-granule p ^ (m&7).
//
// NEW (r6): XCD-aware block swizzle. xcd = blockIdx%8 (dispatch heuristic,
// speed-only). Each XCD owns a contiguous chunk of 16 M-tiles x all 10
// N-tiles = 160 blocks = exactly co-resident (5 blocks/CU x 32 CU at 32KB
// LDS). Per-XCD working set: A 5.2MB + Wrot 3.3MB -> L2/L3-resident, so
// the 4.4x HBM A re-fetch measured in r4 (184MB vs 46MB ideal) collapses.
// ---------------------------------------------------------------------------
#define BM 128
#define BN 128
#define BK 64

__global__ __launch_bounds__(256)
void gemm_bt(const __hip_bfloat16* __restrict__ A,   // [M,K] bf16
             const __hip_bfloat16* __restrict__ B,   // [N,K] bf16
             float* __restrict__ C,                  // [M,N] fp32
             int M, int N, int K) {
    __shared__ bf16x8 As[1024];   // 128 rows * 8 granules * 16B = 16 KiB
    __shared__ bf16x8 Bs[1024];

    const int tid  = threadIdx.x;
    const int wave = tid >> 6;
    const int lane = tid & 63;
    const int q    = lane >> 4;
    const int r16  = lane & 15;

    // XCD-partitioned tile assignment (grid = nTilesM * nTilesN, 8 | nTilesM)
    const int nTilesN = N / BN;               // 10
    const int nTilesM = M / BM;               // 128
    const int chunk   = nTilesM >> 3;         // 16 M-tiles per XCD
    const int xcd = blockIdx.x & 7;
    const int s   = blockIdx.x >> 3;          // sequence within XCD, 0..159
    const int bm  = xcd * chunk + s / nTilesN;
    const int bn  = s % nTilesN;
    const int tileM = bm * BM, tileN = bn * BN;
    const int wm = wave >> 1, wn = wave & 1;

    floatx4 acc[4][4];
#pragma unroll
    for (int i = 0; i < 4; ++i)
#pragma unroll
        for (int j = 0; j < 4; ++j) acc[i][j] = (floatx4){0.f, 0.f, 0.f, 0.f};

    // staging granule for chunk t: g = wave*256 + t*64 + lane
    // row m = g>>3, phys slot p = g&7, data k-granule kv = p ^ (m&7)
    for (int kt = 0; kt < K; kt += BK) {
#pragma unroll
        for (int t = 0; t < 4; ++t) {
            const int g  = wave * 256 + t * 64 + lane;
            const int m  = g >> 3;
            const int kv = (g & 7) ^ (m & 7);
            async_copy16(&As[wave * 256 + t * 64],
                         A + (size_t)(tileM + m) * K + kt + kv * 8);
            async_copy16(&Bs[wave * 256 + t * 64],
                         B + (size_t)(tileN + m) * K + kt + kv * 8);
        }
        __syncthreads();   // drains vmcnt (global_load_lds) + barrier

#pragma unroll
        for (int s2 = 0; s2 < 2; ++s2) {
            bf16x8 af[4], bfr[4];
            const int kv = s2 * 4 + q;
#pragma unroll
            for (int i = 0; i < 4; ++i) {
                const int m = wm * 64 + i * 16 + r16;
                af[i] = As[m * 8 + (kv ^ (m & 7))];
                const int n = wn * 64 + i * 16 + r16;
                bfr[i] = Bs[n * 8 + (kv ^ (n & 7))];
            }
#pragma unroll
            for (int i = 0; i < 4; ++i)
#pragma unroll
                for (int j = 0; j < 4; ++j)
                    acc[i][j] = __builtin_amdgcn_mfma_f32_16x16x32_bf16(
                        af[i], bfr[j], acc[i][j], 0, 0, 0);
        }
        __syncthreads();
    }

    // epilogue: C/D layout col=lane&15, row=quad*4+reg (m89/m91)
#pragma unroll
    for (int i = 0; i < 4; ++i) {
#pragma unroll
        for (int j = 0; j < 4; ++j) {
            const int col = tileN + wn * 64 + j * 16 + r16;
#pragma unroll
            for (int r = 0; r < 4; ++r) {
                const int row = tileM + wm * 64 + i * 16 + q * 4 + r;
                C[(size_t)row * N + col] = acc[i][j][r];
            }
        }
    }
}

// ---------------------------------------------------------------------------
extern "C" void kernel_launch(void* const* d_in, const int* in_sizes, int n_in,
                              void* d_out, int out_size, void* d_ws, size_t ws_size,
                              hipStream_t stream) {
    const float* x  = (const float*)d_in[0];  // [4,4096,1280] fp32
    const float* W  = (const float*)d_in[1];  // [1280,1280]  fp32
    const float* K1 = (const float*)d_in[2];  // [4,4]
    const float* K2 = (const float*)d_in[3];  // [8,8]
    const float* K3 = (const float*)d_in[4];  // [40,40]
    float* out = (float*)d_out;               // [4,4096,1280] fp32

    const int D = 1280;
    const int M = in_sizes[0] / D;            // 16384
    const int N = D, K = D;

    // ws layout: [0, M*K) bf16 x ; then [+, N*K) bf16 Wrot
    __hip_bfloat16* x_bf = (__hip_bfloat16*)d_ws;
    __hip_bfloat16* Wrot = x_bf + (size_t)M * K;

    const int nConv = (M * K) / (256 * 8);    // 10240
    prep<<<nConv + D, 256, 0, stream>>>(x, W, K1, K2, K3, x_bf, Wrot, nConv);
    gemm_bt<<<(M / BM) * (N / BN), 256, 0, stream>>>(x_bf, Wrot, out, M, N, K);
}